// Round 6
// baseline (1102.828 us; speedup 1.0000x reference)
//
#include <hip/hip_runtime.h>
#include <hip/hip_bf16.h>

// GCN 2-layer: N=100000, E=3200000, F 512->16->40, fp32 in/out.
// Pipeline: bucket-hist -> scan -> LDS counting-sort binning (bucket-grouped
// edge array `binned`, packed (dlow<<20)|src) -> buildlite (dinv only) ->
// GEMM1 (W-in-regs, butterfly, unscaled bf16 h1) ->
// agg1: per-bucket LDS-atomic aggregation + bias/relu -> hs2 (unscaled bf16) ->
// agg2: same aggregation + W2 + b2 + log_softmax fused.
// No CSR: saves csr write + 2 reads + scatter; LDS acc padded stride 17.

#define NF0 512
#define NF1 16
#define NF2 40
#define BSHIFT 7            // 128 nodes per bucket
#define BNODES 128
#define CHUNK 8192          // edges per binsort block
#define ETILE 1024          // staged edges per agg tile

typedef float floatx4 __attribute__((ext_vector_type(4)));  // native vec for nontemporal

// bf16 pair helpers: uint u = bf16(lo) | bf16(hi)<<16
__device__ __forceinline__ float bflo(unsigned int u) { return __uint_as_float(u << 16); }
__device__ __forceinline__ float bfhi(unsigned int u) { return __uint_as_float(u & 0xFFFF0000u); }
__device__ __forceinline__ unsigned int packbf(float lo, float hi) {
    unsigned int bl = __float_as_uint(lo);
    bl = (bl + 0x7FFFu + ((bl >> 16) & 1u)) >> 16;
    unsigned int bh = __float_as_uint(hi);
    bh = (bh + 0x7FFFu + ((bh >> 16) & 1u)) & 0xFFFF0000u;
    return bl | bh;
}

// ---------------- bucket histogram ----------------

__global__ void k_zero(int* __restrict__ p, int n) {
    int i = blockIdx.x * 256 + threadIdx.x;
    if (i < n) p[i] = 0;
}

__global__ __launch_bounds__(256) void k_hist(const int* __restrict__ dst,
                                              int* __restrict__ bhist, int E, int NB) {
    extern __shared__ int lh[];
    for (int i = threadIdx.x; i < NB; i += 256) lh[i] = 0;
    __syncthreads();
    for (int e = blockIdx.x * 256 + threadIdx.x; e < E; e += gridDim.x * 256)
        atomicAdd(&lh[dst[e] >> BSHIFT], 1);
    __syncthreads();
    for (int i = threadIdx.x; i < NB; i += 256) {
        int c = lh[i];
        if (c) atomicAdd(&bhist[i], c);
    }
}

__global__ __launch_bounds__(1024) void k_scan(const int* __restrict__ bhist,
                                               int* __restrict__ bstart,
                                               int* __restrict__ cursor, int NB) {
    __shared__ int s[1024];
    int t = threadIdx.x;
    s[t] = (t < NB) ? bhist[t] : 0;
    __syncthreads();
    for (int off = 1; off < 1024; off <<= 1) {
        int y = (t >= off) ? s[t - off] : 0;
        __syncthreads();
        s[t] += y;
        __syncthreads();
    }
    if (t < NB) {
        int excl = (t > 0) ? s[t - 1] : 0;
        bstart[t] = excl;
        cursor[t] = excl;
    }
    if (t == NB) bstart[NB] = s[NB - 1];
}

// ---------------- binning: counting sort CHUNK edges by bucket in LDS ----------------

__global__ __launch_bounds__(256) void k_binsort(
    const int* __restrict__ src, const int* __restrict__ dst,
    int* __restrict__ cursor, unsigned int* __restrict__ binned, int E, int NB) {
    __shared__ unsigned int sorted[CHUNK];
    __shared__ unsigned short bid[CHUNK];
    extern __shared__ int dyn[];
    int* hist = dyn;            // NB (reused as local cursor)
    int* lstart = dyn + NB;     // NB
    int* gbase = dyn + 2 * NB;  // NB
    __shared__ int wtot[4];

    const int t = threadIdx.x;
    const int lane = t & 63, wav = t >> 6;
    const int base = blockIdx.x * CHUNK;
    const int ne = min(CHUNK, E - base);

    for (int i = t; i < NB; i += 256) hist[i] = 0;
    __syncthreads();

    for (int i = t; i < ne; i += 256) atomicAdd(&hist[dst[base + i] >> BSHIFT], 1);
    __syncthreads();

    {
        int eb = t * 4;
        int loc[4];
        int tsum = 0;
        #pragma unroll
        for (int q = 0; q < 4; ++q) {
            loc[q] = (eb + q < NB) ? hist[eb + q] : 0;
            tsum += loc[q];
        }
        int v = tsum;
        #pragma unroll
        for (int off = 1; off < 64; off <<= 1) {
            int y = __shfl_up(v, off, 64);
            if (lane >= off) v += y;
        }
        if (lane == 63) wtot[wav] = v;
        __syncthreads();
        int wbase = 0;
        #pragma unroll
        for (int w = 0; w < 4; ++w) wbase += (w < wav) ? wtot[w] : 0;
        int run = wbase + v - tsum;
        #pragma unroll
        for (int q = 0; q < 4; ++q) {
            if (eb + q < NB) lstart[eb + q] = run;
            run += loc[q];
        }
    }
    __syncthreads();

    for (int b = t; b < NB; b += 256) {
        int c = hist[b];
        if (c > 0) gbase[b] = atomicAdd(&cursor[b], c);
        hist[b] = lstart[b];
    }
    __syncthreads();

    for (int i = t; i < ne; i += 256) {
        int d = dst[base + i];
        int s = src[base + i];
        int b = d >> BSHIFT;
        int pos = atomicAdd(&hist[b], 1);
        sorted[pos] = ((unsigned int)(d & (BNODES - 1)) << 20) | (unsigned int)s;
        bid[pos] = (unsigned short)b;
    }
    __syncthreads();

    for (int i = t; i < ne; i += 256) {
        int b = bid[i];
        binned[gbase[b] + (i - lstart[b])] = sorted[i];
    }
}

// ---------------- buildlite: per-bucket deg -> dinv ----------------

__global__ __launch_bounds__(256) void k_buildlite(
    const unsigned int* __restrict__ binned, const int* __restrict__ bstart,
    float* __restrict__ dinv, int n) {
    __shared__ int cnt[BNODES];
    const int b = blockIdx.x;
    const int t = threadIdx.x;
    const int s0 = bstart[b], s1 = bstart[b + 1];
    if (t < BNODES) cnt[t] = 0;
    __syncthreads();
    for (int i = t; i < s1 - s0; i += 256)
        atomicAdd(&cnt[(binned[s0 + i] >> 20) & (BNODES - 1)], 1);
    __syncthreads();
    if (t < BNODES) {
        int node = b * BNODES + t;
        if (node < n) dinv[node] = rsqrtf((float)(cnt[t] + 1));  // + self loop
    }
}

// ---------------- GEMM1: h1[n][c] = bf16( sum_k x[n][k]*W1[k][c] ) (UNSCALED) --------
// One wave per row, barrier-free; W1 in 128 VGPRs; shuffle-butterfly reduce;
// 2-deep row prefetch; nontemporal x reads (read-once, keep L3 for tables).

__global__ __launch_bounds__(256, 2) void k_gemm1(
    const float* __restrict__ x, const float* __restrict__ W1,
    unsigned int* __restrict__ h1, int n) {
    const int lane = threadIdx.x & 63;
    const int wav = threadIdx.x >> 6;

    float wA[4][16], wB[4][16];
    const float4* W1v = (const float4*)W1;
    #pragma unroll
    for (int j = 0; j < 4; ++j) {
        #pragma unroll
        for (int q = 0; q < 4; ++q) {
            float4 wa = W1v[(4 * lane + j) * 4 + q];
            wA[j][4 * q + 0] = wa.x; wA[j][4 * q + 1] = wa.y;
            wA[j][4 * q + 2] = wa.z; wA[j][4 * q + 3] = wa.w;
            float4 wb = W1v[(256 + 4 * lane + j) * 4 + q];
            wB[j][4 * q + 0] = wb.x; wB[j][4 * q + 1] = wb.y;
            wB[j][4 * q + 2] = wb.z; wB[j][4 * q + 3] = wb.w;
        }
    }

    const floatx4* xv = (const floatx4*)x;
    const int stride = gridDim.x * 4;

    auto process = [&](floatx4 p0, floatx4 p1, int r) {
        float part[16];
        #pragma unroll
        for (int c = 0; c < 16; ++c) part[c] = 0.f;
        float av[8] = {p0.x, p0.y, p0.z, p0.w, p1.x, p1.y, p1.z, p1.w};
        #pragma unroll
        for (int j = 0; j < 4; ++j) {
            #pragma unroll
            for (int c = 0; c < 16; ++c) {
                part[c] = fmaf(av[j], wA[j][c], part[c]);
                part[c] = fmaf(av[4 + j], wB[j][c], part[c]);
            }
        }
        const bool h5 = (lane & 32) != 0;
        float v8[8];
        #pragma unroll
        for (int j = 0; j < 8; ++j)
            v8[j] = (h5 ? part[j + 8] : part[j]) +
                    __shfl_xor(h5 ? part[j] : part[j + 8], 32, 64);
        const bool h4 = (lane & 16) != 0;
        float v4[4];
        #pragma unroll
        for (int j = 0; j < 4; ++j)
            v4[j] = (h4 ? v8[j + 4] : v8[j]) +
                    __shfl_xor(h4 ? v8[j] : v8[j + 4], 16, 64);
        const bool h3 = (lane & 8) != 0;
        float v2[2];
        #pragma unroll
        for (int j = 0; j < 2; ++j)
            v2[j] = (h3 ? v4[j + 2] : v4[j]) +
                    __shfl_xor(h3 ? v4[j] : v4[j + 2], 8, 64);
        const bool h2 = (lane & 4) != 0;
        float v1 = (h2 ? v2[1] : v2[0]) +
                   __shfl_xor(h2 ? v2[0] : v2[1], 4, 64);
        v1 += __shfl_xor(v1, 2, 64);
        v1 += __shfl_xor(v1, 1, 64);
        // every lane holds col (lane>>2); pair cols (2p,2p+1) on lanes 8p
        float vnext = __shfl_down(v1, 4, 64);
        if ((lane & 7) == 0)
            h1[(size_t)r * 8 + (lane >> 3)] = packbf(v1, vnext);
    };

    int r0 = blockIdx.x * 4 + wav;
    int r1 = r0 + stride;
    floatx4 a0, a1, b0, b1;
    if (r0 < n) {
        a0 = __builtin_nontemporal_load(&xv[(size_t)r0 * 128 + lane]);
        a1 = __builtin_nontemporal_load(&xv[(size_t)r0 * 128 + 64 + lane]);
    }
    if (r1 < n) {
        b0 = __builtin_nontemporal_load(&xv[(size_t)r1 * 128 + lane]);
        b1 = __builtin_nontemporal_load(&xv[(size_t)r1 * 128 + 64 + lane]);
    }

    while (r0 < n) {
        floatx4 ca0 = a0, ca1 = a1;
        int pr = r0 + 2 * stride;
        if (pr < n) {
            a0 = __builtin_nontemporal_load(&xv[(size_t)pr * 128 + lane]);
            a1 = __builtin_nontemporal_load(&xv[(size_t)pr * 128 + 64 + lane]);
        }
        process(ca0, ca1, r0);
        if (r1 < n) {
            floatx4 cb0 = b0, cb1 = b1;
            int pr2 = r1 + 2 * stride;
            if (pr2 < n) {
                b0 = __builtin_nontemporal_load(&xv[(size_t)pr2 * 128 + lane]);
                b1 = __builtin_nontemporal_load(&xv[(size_t)pr2 * 128 + 64 + lane]);
            }
            process(cb0, cb1, r1);
        }
        r0 += 2 * stride;
        r1 += 2 * stride;
    }
}

// ---------------- agg core: per-bucket LDS-atomic aggregation ----------------
// acc[dlow*17 + f] += dinv[src] * h[src][f]; stride 17 spreads banks.

__device__ __forceinline__ void agg_edges(
    const unsigned int* __restrict__ binned, int s0, int ne,
    const unsigned int* __restrict__ htab, const float* __restrict__ dinv,
    float* __restrict__ acc, unsigned int* __restrict__ etile, int t) {
    const int p = t & 7;
    for (int base = 0; base < ne; base += ETILE) {
        int m = min(ETILE, ne - base);
        __syncthreads();
        for (int i = t; i < m; i += 256) etile[i] = binned[s0 + base + i];
        __syncthreads();
        int i = t >> 3;
        for (; i + 96 < m; i += 128) {
            unsigned int v0 = etile[i], v1 = etile[i + 32];
            unsigned int v2 = etile[i + 64], v3 = etile[i + 96];
            int s0i = v0 & 0xFFFFF, s1i = v1 & 0xFFFFF;
            int s2i = v2 & 0xFFFFF, s3i = v3 & 0xFFFFF;
            unsigned int u0 = htab[(size_t)s0i * 8 + p];
            unsigned int u1 = htab[(size_t)s1i * 8 + p];
            unsigned int u2 = htab[(size_t)s2i * 8 + p];
            unsigned int u3 = htab[(size_t)s3i * 8 + p];
            float d0 = dinv[s0i], d1 = dinv[s1i], d2 = dinv[s2i], d3 = dinv[s3i];
            int a0 = ((v0 >> 20) & (BNODES - 1)) * 17 + 2 * p;
            int a1 = ((v1 >> 20) & (BNODES - 1)) * 17 + 2 * p;
            int a2 = ((v2 >> 20) & (BNODES - 1)) * 17 + 2 * p;
            int a3 = ((v3 >> 20) & (BNODES - 1)) * 17 + 2 * p;
            atomicAdd(&acc[a0], d0 * bflo(u0)); atomicAdd(&acc[a0 + 1], d0 * bfhi(u0));
            atomicAdd(&acc[a1], d1 * bflo(u1)); atomicAdd(&acc[a1 + 1], d1 * bfhi(u1));
            atomicAdd(&acc[a2], d2 * bflo(u2)); atomicAdd(&acc[a2 + 1], d2 * bfhi(u2));
            atomicAdd(&acc[a3], d3 * bflo(u3)); atomicAdd(&acc[a3 + 1], d3 * bfhi(u3));
        }
        for (; i < m; i += 32) {
            unsigned int v = etile[i];
            int s = v & 0xFFFFF;
            unsigned int u = htab[(size_t)s * 8 + p];
            float d = dinv[s];
            int a = ((v >> 20) & (BNODES - 1)) * 17 + 2 * p;
            atomicAdd(&acc[a], d * bflo(u));
            atomicAdd(&acc[a + 1], d * bfhi(u));
        }
    }
    __syncthreads();
}

// agg1: + self, *dinv_dst, +b1, relu -> hs2 (unscaled bf16)
__global__ __launch_bounds__(256) void k_agg1(
    const unsigned int* __restrict__ binned, const int* __restrict__ bstart,
    const unsigned int* __restrict__ h1, const float* __restrict__ dinv,
    const float* __restrict__ b1, unsigned int* __restrict__ hs2, int n) {
    __shared__ float acc[BNODES * 17];
    __shared__ unsigned int etile[ETILE];
    const int b = blockIdx.x;
    const int t = threadIdx.x;
    const int s0 = bstart[b], ne = bstart[b + 1] - s0;

    for (int i = t; i < BNODES * 17; i += 256) acc[i] = 0.f;
    agg_edges(binned, s0, ne, h1, dinv, acc, etile, t);

    const int p = t & 7;
    float bL = b1[2 * p], bH = b1[2 * p + 1];
    for (int nl = t >> 3; nl < BNODES; nl += 32) {
        int node = b * BNODES + nl;
        if (node >= n) continue;
        unsigned int u = h1[(size_t)node * 8 + p];
        float dn = dinv[node];
        float lo = acc[nl * 17 + 2 * p] + dn * bflo(u);
        float hi = acc[nl * 17 + 2 * p + 1] + dn * bfhi(u);
        float vL = fmaf(dn, lo, bL);
        float vH = fmaf(dn, hi, bH);
        hs2[(size_t)node * 8 + p] = packbf(fmaxf(vL, 0.f), fmaxf(vH, 0.f));
    }
}

// agg2: + self, *dinv_dst, then logits = agg@W2+b2, log_softmax -> out
__global__ __launch_bounds__(256) void k_agg2f(
    const unsigned int* __restrict__ binned, const int* __restrict__ bstart,
    const unsigned int* __restrict__ hs2, const float* __restrict__ dinv,
    const float* __restrict__ W2, const float* __restrict__ b2,
    float* __restrict__ out, int n) {
    __shared__ float acc[BNODES * 17];
    __shared__ unsigned int etile[ETILE];
    __shared__ float w2s[NF1 * NF2];
    __shared__ float b2s[NF2];
    const int b = blockIdx.x;
    const int t = threadIdx.x;
    const int s0 = bstart[b], ne = bstart[b + 1] - s0;

    for (int i = t; i < BNODES * 17; i += 256) acc[i] = 0.f;
    for (int i = t; i < NF1 * NF2; i += 256) w2s[i] = W2[i];
    if (t < NF2) b2s[t] = b2[t];
    agg_edges(binned, s0, ne, hs2, dinv, acc, etile, t);

    // finalize agg in place: acc[nl][f] = dinv_dst * (acc + dinv_dst*self)
    const int p = t & 7;
    for (int nl = t >> 3; nl < BNODES; nl += 32) {
        int node = b * BNODES + nl;
        if (node >= n) continue;
        unsigned int u = hs2[(size_t)node * 8 + p];
        float dn = dinv[node];
        acc[nl * 17 + 2 * p] = dn * (acc[nl * 17 + 2 * p] + dn * bflo(u));
        acc[nl * 17 + 2 * p + 1] = dn * (acc[nl * 17 + 2 * p + 1] + dn * bfhi(u));
    }
    __syncthreads();

    const int wav = t >> 6, lane = t & 63;
    for (int nl = wav; nl < BNODES; nl += 4) {
        int node = b * BNODES + nl;
        if (node >= n) continue;  // uniform per wave
        float av[16];
        #pragma unroll
        for (int k = 0; k < 16; ++k) av[k] = acc[nl * 17 + k];
        float d = -1e30f;
        if (lane < NF2) {
            d = b2s[lane];
            #pragma unroll
            for (int k = 0; k < 16; ++k) d = fmaf(av[k], w2s[k * NF2 + lane], d);
        }
        float m = d;
        #pragma unroll
        for (int off = 32; off; off >>= 1) m = fmaxf(m, __shfl_xor(m, off, 64));
        float e2 = (lane < NF2) ? __expf(d - m) : 0.f;
        float ssum = e2;
        #pragma unroll
        for (int off = 32; off; off >>= 1) ssum += __shfl_xor(ssum, off, 64);
        float ls = __logf(ssum);
        if (lane < NF2) out[(size_t)node * NF2 + lane] = d - m - ls;
    }
}

// ---------------- launch ----------------

extern "C" void kernel_launch(void* const* d_in, const int* in_sizes, int n_in,
                              void* d_out, int out_size, void* d_ws, size_t ws_size,
                              hipStream_t stream) {
    const float* x  = (const float*)d_in[0];
    const int*   ei = (const int*)d_in[1];
    const float* W1 = (const float*)d_in[2];
    const float* b1 = (const float*)d_in[3];
    const float* W2 = (const float*)d_in[4];
    const float* b2 = (const float*)d_in[5];
    float* out = (float*)d_out;

    const int N = in_sizes[0] / NF0;  // 100000
    const int E = in_sizes[1] / 2;    // 3200000
    const int NB = (N + BNODES - 1) / BNODES;  // 782
    const int* src = ei;
    const int* dst = ei + E;

    char* ws = (char*)d_ws;
    size_t off = 0;
    auto alloc = [&](size_t bytes) -> void* {
        void* p = ws + off;
        off = (off + bytes + 255) & ~(size_t)255;
        return p;
    };
    int*   bhist  = (int*)alloc((size_t)NB * 4);
    int*   bstart = (int*)alloc((size_t)(NB + 1) * 4);
    int*   cursor = (int*)alloc((size_t)NB * 4);
    unsigned int* binned = (unsigned int*)alloc((size_t)E * 4);
    float* dinv   = (float*)alloc((size_t)N * 4);
    unsigned int* h1  = (unsigned int*)alloc((size_t)N * 8 * 4);
    unsigned int* hs2 = (unsigned int*)alloc((size_t)N * 8 * 4);

    const int eb = (E + CHUNK - 1) / CHUNK;  // 391
    const size_t histBytes = (size_t)NB * 4;

    k_zero     <<<(NB + 255) / 256, 256, 0, stream>>>(bhist, NB);
    k_hist     <<<512, 256, histBytes, stream>>>(dst, bhist, E, NB);
    k_scan     <<<1, 1024, 0, stream>>>(bhist, bstart, cursor, NB);
    k_binsort  <<<eb, 256, 3 * histBytes, stream>>>(src, dst, cursor, binned, E, NB);
    k_buildlite<<<NB, 256, 0, stream>>>(binned, bstart, dinv, N);
    k_gemm1    <<<1024, 256, 0, stream>>>(x, W1, h1, N);
    k_agg1     <<<NB, 256, 0, stream>>>(binned, bstart, h1, dinv, b1, hs2, N);
    k_agg2f    <<<NB, 256, 0, stream>>>(binned, bstart, hs2, dinv, W2, b2, out, N);
}